// Round 6
// baseline (215.244 us; speedup 1.0000x reference)
//
#include <hip/hip_runtime.h>
#include <hip/hip_bf16.h>
#include <math.h>

// fp32 I/O confirmed. index_sample is int32.
// R9: no mega-atomic fan-in. R10: disjoint non-atomic partials (Oc/Lc).
// R11: k_attn T14 async-STAGE + LDS dbuf; k_cumsum 2-level scan.
// R12: no-op (hints ignored). R13: k_attn de-lambda WORKED; k_measure
// hints FAILED. R14: coalesced all-heads layout: shape fixed, dur same.
// R15: sched_barrier pipeline: VGPR 40, dur same. LESSON: per-wave
// scheduling is NOT the k_measure lever.
// R16 POST-MORTEM MODEL: per-CU pipes: data-return 17us, DS(shuffles) 13us,
// VALU 15us — overlap requires waves; Occupancy stuck 49% => pay ~sum.
// R16: (a) __launch_bounds__(256,8) occupancy declaration on measure.
// (b) GRID-PACK independent BW work into latency slack (no events under
// graph capture): A = chunksum(512,first)+measure(8192); B = topk(32,first)
// + cumsum-scan(512x4waves) [cumsum only needs chunkSum from A => legal
// before attn]; finalize standalone. 5 launches -> 4.

#define BB 4
#define LL 2048
#define HH 8
#define DD 64
#define SS 40
#define UU 40
#define CC 64
#define LC (LL/CC)    // 32 (cumsum chunking)

#define KC    64      // staged k-tile rows
#define NCH2  8       // k-chunks (256 rows each)
#define UG    2       // u-groups of 20
#define KSUB  4       // 64-row subtiles per chunk
#define KPAD  68      // K/V LDS row stride (floats)
#define PPAD  68

#define NCSB  512     // chunksum blocks in launch A (each: 4 waves x 1 chunk)
#define NMSB  (BB*LL) // measure blocks in launch A
#define NTKB  32      // topk blocks in launch B
#define NCUB  512     // cumsum blocks in launch B (each: 4 waves x 1 chunk)

// ---------------------------------------------------------------------------
// LAUNCH A: chunksum role (blocks 0..511, dispatched first, hides under
// measure) + measure role (blocks 512..8703).
// measure: block=(b,i), wave w owns samples w*10..w*10+9; 2KB sample row
// covers all 8 heads (hg=lane>>4 -> h=hg,4+hg; d4=lane&15; lane*16B).
// R15 depth-2 pipeline + sched_barrier retained.
// ---------------------------------------------------------------------------
__launch_bounds__(256, 8)
__global__ void k_measure_cs(const float* __restrict__ Q, const float* __restrict__ K,
                             const float* __restrict__ V, const int* __restrict__ idx,
                             float* __restrict__ M, float* __restrict__ chunkSum)
{
    __shared__ float sMax[4][8];
    __shared__ float sSum[4][8];

    int t = threadIdx.x;

    if (blockIdx.x < NCSB) {
        // ---- chunksum role: wave handles one (bh, c) ----
        int w = t >> 6, lane = t & 63;
        int cI = blockIdx.x * 4 + w;          // 0..2047
        int bh = cI >> 6, c = cI & (CC - 1);
        int b  = bh >> 3, h = bh & 7;
        int d4 = lane & 15, rs = lane >> 4;

        float4 acc = {0,0,0,0};
        int l0 = c * LC;
        for (int l = l0 + rs; l < l0 + LC; l += 4) {
            float4 v = *(const float4*)(V + (((size_t)b * LL + l) * HH + h) * DD + d4 * 4);
            acc.x += v.x; acc.y += v.y; acc.z += v.z; acc.w += v.w;
        }
        acc.x += __shfl_xor(acc.x, 16); acc.y += __shfl_xor(acc.y, 16);
        acc.z += __shfl_xor(acc.z, 16); acc.w += __shfl_xor(acc.w, 16);
        acc.x += __shfl_xor(acc.x, 32); acc.y += __shfl_xor(acc.y, 32);
        acc.z += __shfl_xor(acc.z, 32); acc.w += __shfl_xor(acc.w, 32);
        if (lane < 16)
            *(float4*)(chunkSum + ((size_t)bh * CC + c) * DD + d4 * 4) = acc;
        return;
    }

    // ---- measure role ----
    int blk = blockIdx.x - NCSB;
    int b   = blk >> 11;              // / LL
    int i   = blk & (LL - 1);
    int w    = t >> 6, lane = t & 63;
    int hg   = lane >> 4;             // h group: covers h=hg and h=4+hg
    int d4   = lane & 15;             // float4 slice of d

    const int*   ip   = idx + (size_t)i * SS + w * 10;        // wave-uniform
    const float* Kb   = K + (size_t)b * (LL * HH * DD);
    const float* Qrow = Q + ((size_t)b * LL + i) * (HH * DD);

    float4 qa = *(const float4*)(Qrow + hg * DD + d4 * 4);        // h = hg
    float4 qb = *(const float4*)(Qrow + (4 + hg) * DD + d4 * 4);  // h = 4+hg

    float maxa = -INFINITY, suma = 0.f;
    float maxb = -INFINITY, sumb = 0.f;

#define DOT4(q_, k_) (fmaf((q_).w, (k_).w, fmaf((q_).z, (k_).z, \
                      fmaf((q_).y, (k_).y, (q_).x * (k_).x))))

    float4 A0, B0, A1, B1;   // current group
    float4 A2, B2, A3, B3;   // next group
    {
        int k0 = ip[0], k1 = ip[1];
        const float* r0 = Kb + (size_t)k0 * (HH * DD);
        const float* r1 = Kb + (size_t)k1 * (HH * DD);
        A0 = *(const float4*)(r0 + hg * DD + d4 * 4);
        B0 = *(const float4*)(r0 + (4 + hg) * DD + d4 * 4);
        A1 = *(const float4*)(r1 + hg * DD + d4 * 4);
        B1 = *(const float4*)(r1 + (4 + hg) * DD + d4 * 4);
    }

    #pragma unroll
    for (int g = 0; g < 5; ++g) {
        if (g < 4) {   // issue next group BEFORE computing current
            int k2 = ip[2 * g + 2], k3 = ip[2 * g + 3];
            const float* r2 = Kb + (size_t)k2 * (HH * DD);
            const float* r3 = Kb + (size_t)k3 * (HH * DD);
            A2 = *(const float4*)(r2 + hg * DD + d4 * 4);
            B2 = *(const float4*)(r2 + (4 + hg) * DD + d4 * 4);
            A3 = *(const float4*)(r3 + hg * DD + d4 * 4);
            B3 = *(const float4*)(r3 + (4 + hg) * DD + d4 * 4);
        }
        __builtin_amdgcn_sched_barrier(0);   // loads stay above

        float pa0 = DOT4(qa, A0), pb0 = DOT4(qb, B0);
        float pa1 = DOT4(qa, A1), pb1 = DOT4(qb, B1);
        #pragma unroll
        for (int off = 1; off < 16; off <<= 1) {
            pa0 += __shfl_xor(pa0, off);
            pb0 += __shfl_xor(pb0, off);
            pa1 += __shfl_xor(pa1, off);
            pb1 += __shfl_xor(pb1, off);
        }
        maxa = fmaxf(maxa, fmaxf(pa0, pa1));  suma += pa0 + pa1;
        maxb = fmaxf(maxb, fmaxf(pb0, pb1));  sumb += pb0 + pb1;

        A0 = A2; B0 = B2; A1 = A3; B1 = B3;
    }
#undef DOT4

    if (d4 == 0) {
        sMax[w][hg]     = maxa;  sSum[w][hg]     = suma;
        sMax[w][4 + hg] = maxb;  sSum[w][4 + hg] = sumb;
    }
    __syncthreads();

    if (t < 8) {
        float mx = sMax[0][t], sm = sSum[0][t];
        #pragma unroll
        for (int w2 = 1; w2 < 4; ++w2) {
            mx = fmaxf(mx, sMax[w2][t]);
            sm += sSum[w2][t];
        }
        M[((size_t)(b * HH + t)) * LL + i] = mx - sm * (1.0f / (float)LL);
    }
}

// ---------------------------------------------------------------------------
// LAUNCH B: topk role (blocks 0..31, first — blocks attn) + cumsum-scan
// role (blocks 32..543; wave handles one (bh, c); R11-proven 2-level scan).
// cumsum only needs chunkSum (launch A) => legal before attn.
// ---------------------------------------------------------------------------
__global__ void k_topk_cum(const float* __restrict__ M, int* __restrict__ topIdx,
                           const float* __restrict__ V, const float* __restrict__ chunkSum,
                           float* __restrict__ out)
{
    if (blockIdx.x < NTKB) {
        if (threadIdx.x >= 64) return;
        int lane = threadIdx.x;      // 64
        int bh   = blockIdx.x;
        const float* Mp = M + (size_t)bh * LL;

        unsigned k[32];
        #pragma unroll
        for (int r = 0; r < 32; ++r) {
            unsigned u = __float_as_uint(Mp[r * 64 + lane]);
            k[r] = (u & 0x80000000u) ? ~u : (u | 0x80000000u);  // order-preserving
        }

        unsigned T = 0u;
        for (int bit = 31; bit >= 0; --bit) {
            unsigned cand = T | (1u << bit);
            int c = 0;
            #pragma unroll
            for (int r = 0; r < 32; ++r) c += (k[r] >= cand) ? 1 : 0;
            #pragma unroll
            for (int off = 1; off < 64; off <<= 1) c += __shfl_xor(c, off);
            if (c >= UU) T = cand;
        }

        int cGT = 0, cGE = 0;
        #pragma unroll
        for (int r = 0; r < 32; ++r) {
            cGT += (k[r] > T) ? 1 : 0;
            cGE += (k[r] >= T) ? 1 : 0;
        }
        #pragma unroll
        for (int off = 1; off < 64; off <<= 1) {
            cGT += __shfl_xor(cGT, off);
            cGE += __shfl_xor(cGE, off);
        }

        int need = UU - cGT;
        int X = LL;
        if (cGE - cGT != need) {
            int lo2 = 0;
            for (int bit = 10; bit >= 0; --bit) {
                int cand = lo2 | (1 << bit);
                int c = 0;
                #pragma unroll
                for (int r = 0; r < 32; ++r)
                    c += (k[r] == T && (r * 64 + lane) < cand) ? 1 : 0;
                #pragma unroll
                for (int off = 1; off < 64; off <<= 1) c += __shfl_xor(c, off);
                if (c < need) lo2 = cand;
            }
            X = lo2 + 1;
        }

        unsigned inMask = 0u;
        int cnt = 0;
        #pragma unroll
        for (int r = 0; r < 32; ++r) {
            bool in = (k[r] > T) || (k[r] == T && (r * 64 + lane) < X);
            if (in) { inMask |= 1u << r; ++cnt; }
        }
        int pre = cnt;
        #pragma unroll
        for (int off = 1; off < 64; off <<= 1) {
            int v = __shfl_up(pre, off);
            if (lane >= off) pre += v;
        }
        int slot = pre - cnt;
        #pragma unroll
        for (int r = 0; r < 32; ++r) {
            if ((inMask >> r) & 1u) {
                topIdx[bh * UU + slot] = r * 64 + lane;
                ++slot;
            }
        }
        return;
    }

    // ---- cumsum-scan role: wave handles one (bh, c) ----
    int t    = threadIdx.x;
    int w    = t >> 6, lane = t & 63;
    int cI   = (blockIdx.x - NTKB) * 4 + w;   // 0..2047
    int c    = cI & (CC - 1);
    int bh   = cI >> 6;
    int b    = bh >> 3, h = bh & 7;
    int d4   = lane & 15, s = lane >> 4;      // s: subsegment 0..3 (8 rows each)

    const float4* CS4 = (const float4*)chunkSum;
    float4 off = {0,0,0,0};
    for (int c2 = s; c2 < c; c2 += 4) {
        float4 x = CS4[((size_t)bh * CC + c2) * 16 + d4];
        off.x += x.x; off.y += x.y; off.z += x.z; off.w += x.w;
    }
    off.x += __shfl_xor(off.x, 16); off.y += __shfl_xor(off.y, 16);
    off.z += __shfl_xor(off.z, 16); off.w += __shfl_xor(off.w, 16);
    off.x += __shfl_xor(off.x, 32); off.y += __shfl_xor(off.y, 32);
    off.z += __shfl_xor(off.z, 32); off.w += __shfl_xor(off.w, 32);

    int l0 = c * LC + s * 8;
    size_t base = (((size_t)b * LL + l0) * HH + h) * DD + d4 * 4;
    const size_t stride = (size_t)HH * DD;

    float4 v[8];
    #pragma unroll
    for (int r = 0; r < 8; ++r)
        v[r] = *(const float4*)(V + base + (size_t)r * stride);
    #pragma unroll
    for (int r = 1; r < 8; ++r) {
        v[r].x += v[r-1].x; v[r].y += v[r-1].y;
        v[r].z += v[r-1].z; v[r].w += v[r-1].w;
    }

    float4 inc = v[7];
    float4 p1;
    p1.x = __shfl_up(inc.x, 16); p1.y = __shfl_up(inc.y, 16);
    p1.z = __shfl_up(inc.z, 16); p1.w = __shfl_up(inc.w, 16);
    if (s >= 1) { inc.x += p1.x; inc.y += p1.y; inc.z += p1.z; inc.w += p1.w; }
    float4 p2;
    p2.x = __shfl_up(inc.x, 32); p2.y = __shfl_up(inc.y, 32);
    p2.z = __shfl_up(inc.z, 32); p2.w = __shfl_up(inc.w, 32);
    if (s >= 2) { inc.x += p2.x; inc.y += p2.y; inc.z += p2.z; inc.w += p2.w; }

    float4 add;
    add.x = off.x + inc.x - v[7].x;
    add.y = off.y + inc.y - v[7].y;
    add.z = off.z + inc.z - v[7].z;
    add.w = off.w + inc.w - v[7].w;

    #pragma unroll
    for (int r = 0; r < 8; ++r) {
        float4 o;
        o.x = v[r].x + add.x; o.y = v[r].y + add.y;
        o.z = v[r].z + add.z; o.w = v[r].w + add.w;
        *(float4*)(out + base + (size_t)r * stride) = o;
    }
}

// ---------------------------------------------------------------------------
// K3: attention partials, shift-free softmax, NON-ATOMIC disjoint writes.
// Grid = bh(32) x ch(8) x ug(2) = 512 blocks, 256 threads, 2/CU resident.
// Double-buffered LDS + async-STAGE split (T14). Staging in 8 NAMED float4
// registers (macros, no lambdas/arrays) — R13-proven (killed 64MB scratch).
// ---------------------------------------------------------------------------
__launch_bounds__(256, 2)
__global__ void k_attn(const float* __restrict__ Q, const float* __restrict__ K,
                       const float* __restrict__ V, const int* __restrict__ topIdx,
                       float* __restrict__ Oc, float* __restrict__ Lc)
{
    __shared__ float sK[2][KC][KPAD];
    __shared__ float sV[2][KC][KPAD];
    __shared__ float sP[20][PPAD];
    __shared__ int   sPos[UU];

    int t   = threadIdx.x;
    int bid = blockIdx.x;
    int bh  = bid / (NCH2 * UG);
    int rem = bid % (NCH2 * UG);
    int ch  = rem / UG, ug = rem % UG;
    int b   = bh / HH, h = bh % HH;

    if (t < UU) sPos[t] = topIdx[bh * UU + t];

    int j  = t & 63;                 // QK lane -> k-row within subtile
    int w  = t >> 6, lane = t & 63;  // wave mapping
    int ub = __builtin_amdgcn_readfirstlane(w) * 5;   // local u base (0,5,10,15)

    // PV accumulators: thread = (d4p = t&15, tg = t>>4); local u = tg, 16+tg
    int d4p = t & 15, tg = t >> 4;
    float4 a0 = {0,0,0,0}, a1 = {0,0,0,0};
    float den[5] = {0.f, 0.f, 0.f, 0.f, 0.f};

    const float* Kh = K + ((size_t)b * LL * HH + h) * DD;
    const float* Vh = V + ((size_t)b * LL * HH + h) * DD;

    // staged tile in 8 NAMED float4 regs; thread covers rows it*16+tg, slice d4p
    float4 pk0, pk1, pk2, pk3, pv0, pv1, pv2, pv3;

#define ISSUE(k0_) { \
    size_t g0 = (size_t)((k0_) +  0 + tg) * (HH * DD) + d4p * 4; \
    size_t g1 = (size_t)((k0_) + 16 + tg) * (HH * DD) + d4p * 4; \
    size_t g2 = (size_t)((k0_) + 32 + tg) * (HH * DD) + d4p * 4; \
    size_t g3 = (size_t)((k0_) + 48 + tg) * (HH * DD) + d4p * 4; \
    pk0 = *(const float4*)(Kh + g0); pv0 = *(const float4*)(Vh + g0); \
    pk1 = *(const float4*)(Kh + g1); pv1 = *(const float4*)(Vh + g1); \
    pk2 = *(const float4*)(Kh + g2); pv2 = *(const float4*)(Vh + g2); \
    pk3 = *(const float4*)(Kh + g3); pv3 = *(const float4*)(Vh + g3); \
}
#define COMMIT(buf_) { \
    *(float4*)&sK[buf_][ 0 + tg][d4p * 4] = pk0; *(float4*)&sV[buf_][ 0 + tg][d4p * 4] = pv0; \
    *(float4*)&sK[buf_][16 + tg][d4p * 4] = pk1; *(float4*)&sV[buf_][16 + tg][d4p * 4] = pv1; \
    *(float4*)&sK[buf_][32 + tg][d4p * 4] = pk2; *(float4*)&sV[buf_][32 + tg][d4p * 4] = pv2; \
    *(float4*)&sK[buf_][48 + tg][d4p * 4] = pk3; *(float4*)&sV[buf_][48 + tg][d4p * 4] = pv3; \
}

    int k0base = ch * KSUB * KC;
    ISSUE(k0base);
    COMMIT(0);
    __syncthreads();   // buf0 + sPos ready

    #pragma unroll
    for (int sub = 0; sub < KSUB; ++sub) {
        int cur = sub & 1;
        int k0  = k0base + sub * KC;

        if (sub + 1 < KSUB) ISSUE(k0 + KC);   // async: in flight across QK

        // ---- QK: lane owns k-row j; Q rows via scalar (wave-uniform) loads ----
        int jg = k0 + j;
        {
            int p0 = __builtin_amdgcn_readfirstlane(sPos[ug * 20 + ub + 0]);
            int p1 = __builtin_amdgcn_readfirstlane(sPos[ug * 20 + ub + 1]);
            int p2 = __builtin_amdgcn_readfirstlane(sPos[ug * 20 + ub + 2]);
            int p3 = __builtin_amdgcn_readfirstlane(sPos[ug * 20 + ub + 3]);
            int p4 = __builtin_amdgcn_readfirstlane(sPos[ug * 20 + ub + 4]);
            const float* q0 = Q + (((size_t)b * LL + p0) * HH + h) * DD;
            const float* q1 = Q + (((size_t)b * LL + p1) * HH + h) * DD;
            const float* q2 = Q + (((size_t)b * LL + p2) * HH + h) * DD;
            const float* q3 = Q + (((size_t)b * LL + p3) * HH + h) * DD;
            const float* q4 = Q + (((size_t)b * LL + p4) * HH + h) * DD;
            float c0 = 0.f, c1 = 0.f, c2 = 0.f, c3 = 0.f, c4 = 0.f;
            #pragma unroll
            for (int d4 = 0; d4 < 16; ++d4) {
                float4 kk = *(const float4*)&sK[cur][j][d4 * 4];
                int d = d4 * 4;
                c0 = fmaf(kk.x, q0[d], c0); c0 = fmaf(kk.y, q0[d+1], c0);
                c0 = fmaf(kk.z, q0[d+2], c0); c0 = fmaf(kk.w, q0[d+3], c0);
                c1 = fmaf(kk.x, q1[d], c1); c1 = fmaf(kk.y, q1[d+1], c1);
                c1 = fmaf(kk.z, q1[d+2], c1); c1 = fmaf(kk.w, q1[d+3], c1);
                c2 = fmaf(kk.x, q2[d], c2); c2 = fmaf(kk.y, q2[d+1], c2);
                c2 = fmaf(kk.z, q2[d+2], c2); c2 = fmaf(kk.w, q2[d+3], c2);
                c3 = fmaf(kk.x, q3[d], c3); c3 = fmaf(kk.y, q3[d+1], c3);
                c3 = fmaf(kk.z, q3[d+2], c3); c3 = fmaf(kk.w, q3[d+3], c3);
                c4 = fmaf(kk.x, q4[d], c4); c4 = fmaf(kk.y, q4[d+1], c4);
                c4 = fmaf(kk.z, q4[d+2], c4); c4 = fmaf(kk.w, q4[d+3], c4);
            }
            float e0 = (jg > p0) ? 0.f : __expf(c0 * 0.125f);
            float e1 = (jg > p1) ? 0.f : __expf(c1 * 0.125f);
            float e2 = (jg > p2) ? 0.f : __expf(c2 * 0.125f);
            float e3 = (jg > p3) ? 0.f : __expf(c3 * 0.125f);
            float e4 = (jg > p4) ? 0.f : __expf(c4 * 0.125f);
            sP[ub + 0][j] = e0;
            sP[ub + 1][j] = e1;
            sP[ub + 2][j] = e2;
            sP[ub + 3][j] = e3;
            sP[ub + 4][j] = e4;
            // denominator partials (wave-reduce, accumulate in registers)
            #pragma unroll
            for (int off = 1; off < 64; off <<= 1) {
                e0 += __shfl_xor(e0, off);
                e1 += __shfl_xor(e1, off);
                e2 += __shfl_xor(e2, off);
                e3 += __shfl_xor(e3, off);
                e4 += __shfl_xor(e4, off);
            }
            den[0] += e0; den[1] += e1; den[2] += e2; den[3] += e3; den[4] += e4;
        }
        __syncthreads();   // sP visible; all reads of sK[cur] done

        // ---- write staged regs to the idle buffer (overlaps with PV) ----
        if (sub + 1 < KSUB) {
            if (cur == 0) { COMMIT(1); } else { COMMIT(0); }
        }

        // ---- PV accumulate (reads sP/sV[cur] only) ----
        #pragma unroll 4
        for (int j4 = 0; j4 < KC / 4; ++j4) {
            float4 pj0 = *(const float4*)&sP[tg][j4 * 4];
            float4 pj1 = (tg < 4) ? *(const float4*)&sP[16 + tg][j4 * 4]
                                  : (float4){0,0,0,0};
            float4 va = *(const float4*)&sV[cur][j4 * 4 + 0][d4p * 4];
            float4 vb = *(const float4*)&sV[cur][j4 * 4 + 1][d4p * 4];
            float4 vc = *(const float4*)&sV[cur][j4 * 4 + 2][d4p * 4];
            float4 vd = *(const float4*)&sV[cur][j4 * 4 + 3][d4p * 4];
            a0.x = fmaf(pj0.x, va.x, fmaf(pj0.y, vb.x, fmaf(pj0.z, vc.x, fmaf(pj0.w, vd.x, a0.x))));
            a0.y = fmaf(pj0.x, va.y, fmaf(pj0.y, vb.y, fmaf(pj0.z, vc.y, fmaf(pj0.w, vd.y, a0.y))));
            a0.z = fmaf(pj0.x, va.z, fmaf(pj0.y, vb.z, fmaf(pj0.z, vc.z, fmaf(pj0.w, vd.z, a0.z))));
            a0.w = fmaf(pj0.x, va.w, fmaf(pj0.y, vb.w, fmaf(pj0.z, vc.w, fmaf(pj0.w, vd.w, a0.w))));
            a1.x = fmaf(pj1.x, va.x, fmaf(pj1.y, vb.x, fmaf(pj1.z, vc.x, fmaf(pj1.w, vd.x, a1.x))));
            a1.y = fmaf(pj1.x, va.y, fmaf(pj1.y, vb.y, fmaf(pj1.z, vc.y, fmaf(pj1.w, vd.y, a1.y))));
            a1.z = fmaf(pj1.x, va.z, fmaf(pj1.y, vb.z, fmaf(pj1.z, vc.z, fmaf(pj1.w, vd.z, a1.z))));
            a1.w = fmaf(pj1.x, va.w, fmaf(pj1.y, vb.w, fmaf(pj1.z, vc.w, fmaf(pj1.w, vd.w, a1.w))));
        }
        __syncthreads();   // PV done with sP/sV[cur]; buf^1 writes visible
    }
#undef ISSUE
#undef COMMIT

    // ---- disjoint final writes ----
    if (lane == 0) {
        int base = (bh * NCH2 + ch) * UU + ug * 20 + ub;
        Lc[base + 0] = den[0]; Lc[base + 1] = den[1]; Lc[base + 2] = den[2];
        Lc[base + 3] = den[3]; Lc[base + 4] = den[4];
    }
    {
        int u0g = ug * 20 + tg;
        size_t o0 = ((size_t)(bh * NCH2 + ch) * UU + u0g) * DD + d4p * 4;
        *(float4*)(Oc + o0) = a0;
        if (tg < 4) {
            int u1g = ug * 20 + 16 + tg;
            size_t o1 = ((size_t)(bh * NCH2 + ch) * UU + u1g) * DD + d4p * 4;
            *(float4*)(Oc + o1) = a1;
        }
    }
}

// ---------------------------------------------------------------------------
// K5: finalize — out[pos] = (sum_ch Oc) / (sum_ch Lc). After k_attn.
// Grid = 32 bh, 256 threads (wave w covers u = w*10..+9, lane = d).
// ---------------------------------------------------------------------------
__global__ void k_finalize(const float* __restrict__ Oc, const float* __restrict__ Lc,
                           const int* __restrict__ topIdx, float* __restrict__ out)
{
    int bh = blockIdx.x;
    int b  = bh / HH, h = bh % HH;
    int t  = threadIdx.x;
    int d  = t & 63, w = t >> 6;
    for (int i = 0; i < 10; ++i) {
        int u = w * 10 + i;
        int pos = topIdx[bh * UU + u];
        float num = 0.f, den = 0.f;
        #pragma unroll
        for (int c = 0; c < NCH2; ++c) {
            num += Oc[((size_t)(bh * NCH2 + c) * UU + u) * DD + d];
            den += Lc[(bh * NCH2 + c) * UU + u];
        }
        out[(((size_t)b * LL + pos) * HH + h) * DD + d] = num / den;
    }
}

// ---------------------------------------------------------------------------
extern "C" void kernel_launch(void* const* d_in, const int* in_sizes, int n_in,
                              void* d_out, int out_size, void* d_ws, size_t ws_size,
                              hipStream_t stream)
{
    const float* Q   = (const float*)d_in[0];
    const float* K   = (const float*)d_in[1];
    const float* V   = (const float*)d_in[2];
    const int*   idx = (const int*)d_in[3];
    float* out = (float*)d_out;

    // ws layout (floats) — total ~864K floats ≈ 3.45 MB (R4-proven size)
    float* M        = (float*)d_ws;                               // 65536
    int*   topIdx   = (int*)(M + (size_t)BB * HH * LL);           // 1280
    float* Oc       = (float*)(topIdx + BB * HH * UU);            // 32*8*40*64 = 655360
    float* Lc       = Oc + (size_t)BB * HH * NCH2 * UU * DD;      // 32*8*40 = 10240
    float* chunkSum = Lc + BB * HH * NCH2 * UU;                   // 131072

    k_measure_cs<<<NCSB + NMSB,        256, 0, stream>>>(Q, K, V, idx, M, chunkSum);
    k_topk_cum  <<<NTKB + NCUB,        256, 0, stream>>>(M, topIdx, V, chunkSum, out);
    k_attn      <<<BB * HH * NCH2 * UG, 256, 0, stream>>>(Q, K, V, topIdx, Oc, Lc);
    k_finalize  <<<BB * HH,            256, 0, stream>>>(Oc, Lc, topIdx, out);
}

// Round 7
// 187.687 us; speedup vs baseline: 1.1468x; 1.1468x over previous
//
#include <hip/hip_runtime.h>
#include <hip/hip_bf16.h>
#include <math.h>

// fp32 I/O confirmed. index_sample is int32.
// R9: no mega-atomic fan-in. R10: disjoint non-atomic partials (Oc/Lc).
// R11: k_attn T14 async-STAGE + LDS dbuf; k_cumsum 2-level scan.
// R12: no-op (hints ignored). R13: k_attn de-lambda WORKED; k_measure
// hints FAILED. R14: coalesced all-heads layout: shape fixed, dur same.
// R15: sched_barrier pipeline: no change. R16: launch_bounds(256,8)
// DISASTER — forced VGPR 32 < pipeline live set => scratch spills
// (WRITE 117MB, FETCH 225MB, 85us). ALSO: occupancy 49->75% did NOT help
// => occupancy was never the limiter. RULE: never declare occupancy
// above what the live set affords.
// R17 THEORY: k_measure FETCH==compulsory (~97MB) but only 2.3TB/s —
// random 2KB-granule gather across 67MB kills HBM/DRAM locality.
// Remaining axis = miss-stream locality: process samples bucketed by
// K-tile (8 x 256 rows), all blocks sweep tiles in same order =>
// sequential-ish HBM first-touch + L2 reuse window (~512KB/batch).
// Bucketing is exact (max/sum order-independent). Revert launch_bounds;
// keep grid-pack (A: chunksum+measure, B: topk+cumsum).

#define BB 4
#define LL 2048
#define HH 8
#define DD 64
#define SS 40
#define UU 40
#define CC 64
#define LC (LL/CC)    // 32 (cumsum chunking)

#define KC    64      // staged k-tile rows
#define NCH2  8       // k-chunks (256 rows each)
#define UG    2       // u-groups of 20
#define KSUB  4       // 64-row subtiles per chunk
#define KPAD  68      // K/V LDS row stride (floats)
#define PPAD  68

#define NCSB  512     // chunksum blocks in launch A (each: 4 waves x 1 chunk)
#define NMSB  (BB*LL) // measure blocks in launch A
#define NTKB  32      // topk blocks in launch B
#define NCUB  512     // cumsum blocks in launch B (each: 4 waves x 1 chunk)

// ---------------------------------------------------------------------------
// LAUNCH A: chunksum role (blocks 0..511, dispatched first, hides under
// measure) + measure role (blocks 512..8703).
// measure: block=(b,i), wave w owns samples w*10..w*10+9; 2KB sample row
// covers all 8 heads (hg=lane>>4 -> h=hg,4+hg; d4=lane&15; lane*16B).
// R17: samples processed in K-TILE order (tile = kk>>8, 8 tiles).
// ---------------------------------------------------------------------------
__global__ void k_measure_cs(const float* __restrict__ Q, const float* __restrict__ K,
                             const float* __restrict__ V, const int* __restrict__ idx,
                             float* __restrict__ M, float* __restrict__ chunkSum)
{
    __shared__ float sMax[4][8];
    __shared__ float sSum[4][8];

    int t = threadIdx.x;

    if (blockIdx.x < NCSB) {
        // ---- chunksum role: wave handles one (bh, c) ----
        int w = t >> 6, lane = t & 63;
        int cI = blockIdx.x * 4 + w;          // 0..2047
        int bh = cI >> 6, c = cI & (CC - 1);
        int b  = bh >> 3, h = bh & 7;
        int d4 = lane & 15, rs = lane >> 4;

        float4 acc = {0,0,0,0};
        int l0 = c * LC;
        for (int l = l0 + rs; l < l0 + LC; l += 4) {
            float4 v = *(const float4*)(V + (((size_t)b * LL + l) * HH + h) * DD + d4 * 4);
            acc.x += v.x; acc.y += v.y; acc.z += v.z; acc.w += v.w;
        }
        acc.x += __shfl_xor(acc.x, 16); acc.y += __shfl_xor(acc.y, 16);
        acc.z += __shfl_xor(acc.z, 16); acc.w += __shfl_xor(acc.w, 16);
        acc.x += __shfl_xor(acc.x, 32); acc.y += __shfl_xor(acc.y, 32);
        acc.z += __shfl_xor(acc.z, 32); acc.w += __shfl_xor(acc.w, 32);
        if (lane < 16)
            *(float4*)(chunkSum + ((size_t)bh * CC + c) * DD + d4 * 4) = acc;
        return;
    }

    // ---- measure role ----
    int blk = blockIdx.x - NCSB;
    int b   = blk >> 11;              // / LL
    int i   = blk & (LL - 1);
    int w    = t >> 6, lane = t & 63;
    int hg   = lane >> 4;             // h group: covers h=hg and h=4+hg
    int d4   = lane & 15;             // float4 slice of d

    const int*   ip   = idx + (size_t)i * SS + w * 10;        // wave-uniform
    const float* Kb   = K + (size_t)b * (LL * HH * DD);
    const float* Qrow = Q + ((size_t)b * LL + i) * (HH * DD);

    float4 qa = *(const float4*)(Qrow + hg * DD + d4 * 4);        // h = hg
    float4 qb = *(const float4*)(Qrow + (4 + hg) * DD + d4 * 4);  // h = 4+hg

    float maxa = -INFINITY, suma = 0.f;
    float maxb = -INFINITY, sumb = 0.f;

    // all 10 indices up front (scalar, wave-uniform)
    int kk[10];
    #pragma unroll
    for (int u = 0; u < 10; ++u) kk[u] = ip[u];

#define DOT4(q_, k_) (fmaf((q_).w, (k_).w, fmaf((q_).z, (k_).z, \
                      fmaf((q_).y, (k_).y, (q_).x * (k_).x))))

    // K-tile-ordered processing: tile = kk>>8 (256 rows = 512KB/tile/batch).
    // All blocks sweep tiles 0..7 in order => L2-window reuse, sequential-ish
    // HBM first-touch. Uniform scalar branches; exact (order-independent).
    for (int tile = 0; tile < 8; ++tile) {
        #pragma unroll
        for (int u = 0; u < 10; ++u) {
            if ((kk[u] >> 8) == tile) {
                const float* r = Kb + (size_t)kk[u] * (HH * DD);
                float4 ka = *(const float4*)(r + hg * DD + d4 * 4);
                float4 kb = *(const float4*)(r + (4 + hg) * DD + d4 * 4);
                float pa = DOT4(qa, ka);
                float pb = DOT4(qb, kb);
                #pragma unroll
                for (int off = 1; off < 16; off <<= 1) {
                    pa += __shfl_xor(pa, off);
                    pb += __shfl_xor(pb, off);
                }
                maxa = fmaxf(maxa, pa);  suma += pa;
                maxb = fmaxf(maxb, pb);  sumb += pb;
            }
        }
    }
#undef DOT4

    if (d4 == 0) {
        sMax[w][hg]     = maxa;  sSum[w][hg]     = suma;
        sMax[w][4 + hg] = maxb;  sSum[w][4 + hg] = sumb;
    }
    __syncthreads();

    if (t < 8) {
        float mx = sMax[0][t], sm = sSum[0][t];
        #pragma unroll
        for (int w2 = 1; w2 < 4; ++w2) {
            mx = fmaxf(mx, sMax[w2][t]);
            sm += sSum[w2][t];
        }
        M[((size_t)(b * HH + t)) * LL + i] = mx - sm * (1.0f / (float)LL);
    }
}

// ---------------------------------------------------------------------------
// LAUNCH B: topk role (blocks 0..31, first — blocks attn) + cumsum-scan
// role (blocks 32..543; wave handles one (bh, c); R11-proven 2-level scan).
// cumsum only needs chunkSum (launch A) => legal before attn.
// ---------------------------------------------------------------------------
__global__ void k_topk_cum(const float* __restrict__ M, int* __restrict__ topIdx,
                           const float* __restrict__ V, const float* __restrict__ chunkSum,
                           float* __restrict__ out)
{
    if (blockIdx.x < NTKB) {
        if (threadIdx.x >= 64) return;
        int lane = threadIdx.x;      // 64
        int bh   = blockIdx.x;
        const float* Mp = M + (size_t)bh * LL;

        unsigned k[32];
        #pragma unroll
        for (int r = 0; r < 32; ++r) {
            unsigned u = __float_as_uint(Mp[r * 64 + lane]);
            k[r] = (u & 0x80000000u) ? ~u : (u | 0x80000000u);  // order-preserving
        }

        unsigned T = 0u;
        for (int bit = 31; bit >= 0; --bit) {
            unsigned cand = T | (1u << bit);
            int c = 0;
            #pragma unroll
            for (int r = 0; r < 32; ++r) c += (k[r] >= cand) ? 1 : 0;
            #pragma unroll
            for (int off = 1; off < 64; off <<= 1) c += __shfl_xor(c, off);
            if (c >= UU) T = cand;
        }

        int cGT = 0, cGE = 0;
        #pragma unroll
        for (int r = 0; r < 32; ++r) {
            cGT += (k[r] > T) ? 1 : 0;
            cGE += (k[r] >= T) ? 1 : 0;
        }
        #pragma unroll
        for (int off = 1; off < 64; off <<= 1) {
            cGT += __shfl_xor(cGT, off);
            cGE += __shfl_xor(cGE, off);
        }

        int need = UU - cGT;
        int X = LL;
        if (cGE - cGT != need) {
            int lo2 = 0;
            for (int bit = 10; bit >= 0; --bit) {
                int cand = lo2 | (1 << bit);
                int c = 0;
                #pragma unroll
                for (int r = 0; r < 32; ++r)
                    c += (k[r] == T && (r * 64 + lane) < cand) ? 1 : 0;
                #pragma unroll
                for (int off = 1; off < 64; off <<= 1) c += __shfl_xor(c, off);
                if (c < need) lo2 = cand;
            }
            X = lo2 + 1;
        }

        unsigned inMask = 0u;
        int cnt = 0;
        #pragma unroll
        for (int r = 0; r < 32; ++r) {
            bool in = (k[r] > T) || (k[r] == T && (r * 64 + lane) < X);
            if (in) { inMask |= 1u << r; ++cnt; }
        }
        int pre = cnt;
        #pragma unroll
        for (int off = 1; off < 64; off <<= 1) {
            int v = __shfl_up(pre, off);
            if (lane >= off) pre += v;
        }
        int slot = pre - cnt;
        #pragma unroll
        for (int r = 0; r < 32; ++r) {
            if ((inMask >> r) & 1u) {
                topIdx[bh * UU + slot] = r * 64 + lane;
                ++slot;
            }
        }
        return;
    }

    // ---- cumsum-scan role: wave handles one (bh, c) ----
    int t    = threadIdx.x;
    int w    = t >> 6, lane = t & 63;
    int cI   = (blockIdx.x - NTKB) * 4 + w;   // 0..2047
    int c    = cI & (CC - 1);
    int bh   = cI >> 6;
    int b    = bh >> 3, h = bh & 7;
    int d4   = lane & 15, s = lane >> 4;      // s: subsegment 0..3 (8 rows each)

    const float4* CS4 = (const float4*)chunkSum;
    float4 off = {0,0,0,0};
    for (int c2 = s; c2 < c; c2 += 4) {
        float4 x = CS4[((size_t)bh * CC + c2) * 16 + d4];
        off.x += x.x; off.y += x.y; off.z += x.z; off.w += x.w;
    }
    off.x += __shfl_xor(off.x, 16); off.y += __shfl_xor(off.y, 16);
    off.z += __shfl_xor(off.z, 16); off.w += __shfl_xor(off.w, 16);
    off.x += __shfl_xor(off.x, 32); off.y += __shfl_xor(off.y, 32);
    off.z += __shfl_xor(off.z, 32); off.w += __shfl_xor(off.w, 32);

    int l0 = c * LC + s * 8;
    size_t base = (((size_t)b * LL + l0) * HH + h) * DD + d4 * 4;
    const size_t stride = (size_t)HH * DD;

    float4 v[8];
    #pragma unroll
    for (int r = 0; r < 8; ++r)
        v[r] = *(const float4*)(V + base + (size_t)r * stride);
    #pragma unroll
    for (int r = 1; r < 8; ++r) {
        v[r].x += v[r-1].x; v[r].y += v[r-1].y;
        v[r].z += v[r-1].z; v[r].w += v[r-1].w;
    }

    float4 inc = v[7];
    float4 p1;
    p1.x = __shfl_up(inc.x, 16); p1.y = __shfl_up(inc.y, 16);
    p1.z = __shfl_up(inc.z, 16); p1.w = __shfl_up(inc.w, 16);
    if (s >= 1) { inc.x += p1.x; inc.y += p1.y; inc.z += p1.z; inc.w += p1.w; }
    float4 p2;
    p2.x = __shfl_up(inc.x, 32); p2.y = __shfl_up(inc.y, 32);
    p2.z = __shfl_up(inc.z, 32); p2.w = __shfl_up(inc.w, 32);
    if (s >= 2) { inc.x += p2.x; inc.y += p2.y; inc.z += p2.z; inc.w += p2.w; }

    float4 add;
    add.x = off.x + inc.x - v[7].x;
    add.y = off.y + inc.y - v[7].y;
    add.z = off.z + inc.z - v[7].z;
    add.w = off.w + inc.w - v[7].w;

    #pragma unroll
    for (int r = 0; r < 8; ++r) {
        float4 o;
        o.x = v[r].x + add.x; o.y = v[r].y + add.y;
        o.z = v[r].z + add.z; o.w = v[r].w + add.w;
        *(float4*)(out + base + (size_t)r * stride) = o;
    }
}

// ---------------------------------------------------------------------------
// K3: attention partials, shift-free softmax, NON-ATOMIC disjoint writes.
// Grid = bh(32) x ch(8) x ug(2) = 512 blocks, 256 threads, 2/CU resident.
// Double-buffered LDS + async-STAGE split (T14). Staging in 8 NAMED float4
// registers (macros, no lambdas/arrays) — R13-proven (killed 64MB scratch).
// ---------------------------------------------------------------------------
__launch_bounds__(256, 2)
__global__ void k_attn(const float* __restrict__ Q, const float* __restrict__ K,
                       const float* __restrict__ V, const int* __restrict__ topIdx,
                       float* __restrict__ Oc, float* __restrict__ Lc)
{
    __shared__ float sK[2][KC][KPAD];
    __shared__ float sV[2][KC][KPAD];
    __shared__ float sP[20][PPAD];
    __shared__ int   sPos[UU];

    int t   = threadIdx.x;
    int bid = blockIdx.x;
    int bh  = bid / (NCH2 * UG);
    int rem = bid % (NCH2 * UG);
    int ch  = rem / UG, ug = rem % UG;
    int b   = bh / HH, h = bh % HH;

    if (t < UU) sPos[t] = topIdx[bh * UU + t];

    int j  = t & 63;                 // QK lane -> k-row within subtile
    int w  = t >> 6, lane = t & 63;  // wave mapping
    int ub = __builtin_amdgcn_readfirstlane(w) * 5;   // local u base (0,5,10,15)

    // PV accumulators: thread = (d4p = t&15, tg = t>>4); local u = tg, 16+tg
    int d4p = t & 15, tg = t >> 4;
    float4 a0 = {0,0,0,0}, a1 = {0,0,0,0};
    float den[5] = {0.f, 0.f, 0.f, 0.f, 0.f};

    const float* Kh = K + ((size_t)b * LL * HH + h) * DD;
    const float* Vh = V + ((size_t)b * LL * HH + h) * DD;

    // staged tile in 8 NAMED float4 regs; thread covers rows it*16+tg, slice d4p
    float4 pk0, pk1, pk2, pk3, pv0, pv1, pv2, pv3;

#define ISSUE(k0_) { \
    size_t g0 = (size_t)((k0_) +  0 + tg) * (HH * DD) + d4p * 4; \
    size_t g1 = (size_t)((k0_) + 16 + tg) * (HH * DD) + d4p * 4; \
    size_t g2 = (size_t)((k0_) + 32 + tg) * (HH * DD) + d4p * 4; \
    size_t g3 = (size_t)((k0_) + 48 + tg) * (HH * DD) + d4p * 4; \
    pk0 = *(const float4*)(Kh + g0); pv0 = *(const float4*)(Vh + g0); \
    pk1 = *(const float4*)(Kh + g1); pv1 = *(const float4*)(Vh + g1); \
    pk2 = *(const float4*)(Kh + g2); pv2 = *(const float4*)(Vh + g2); \
    pk3 = *(const float4*)(Kh + g3); pv3 = *(const float4*)(Vh + g3); \
}
#define COMMIT(buf_) { \
    *(float4*)&sK[buf_][ 0 + tg][d4p * 4] = pk0; *(float4*)&sV[buf_][ 0 + tg][d4p * 4] = pv0; \
    *(float4*)&sK[buf_][16 + tg][d4p * 4] = pk1; *(float4*)&sV[buf_][16 + tg][d4p * 4] = pv1; \
    *(float4*)&sK[buf_][32 + tg][d4p * 4] = pk2; *(float4*)&sV[buf_][32 + tg][d4p * 4] = pv2; \
    *(float4*)&sK[buf_][48 + tg][d4p * 4] = pk3; *(float4*)&sV[buf_][48 + tg][d4p * 4] = pv3; \
}

    int k0base = ch * KSUB * KC;
    ISSUE(k0base);
    COMMIT(0);
    __syncthreads();   // buf0 + sPos ready

    #pragma unroll
    for (int sub = 0; sub < KSUB; ++sub) {
        int cur = sub & 1;
        int k0  = k0base + sub * KC;

        if (sub + 1 < KSUB) ISSUE(k0 + KC);   // async: in flight across QK

        // ---- QK: lane owns k-row j; Q rows via scalar (wave-uniform) loads ----
        int jg = k0 + j;
        {
            int p0 = __builtin_amdgcn_readfirstlane(sPos[ug * 20 + ub + 0]);
            int p1 = __builtin_amdgcn_readfirstlane(sPos[ug * 20 + ub + 1]);
            int p2 = __builtin_amdgcn_readfirstlane(sPos[ug * 20 + ub + 2]);
            int p3 = __builtin_amdgcn_readfirstlane(sPos[ug * 20 + ub + 3]);
            int p4 = __builtin_amdgcn_readfirstlane(sPos[ug * 20 + ub + 4]);
            const float* q0 = Q + (((size_t)b * LL + p0) * HH + h) * DD;
            const float* q1 = Q + (((size_t)b * LL + p1) * HH + h) * DD;
            const float* q2 = Q + (((size_t)b * LL + p2) * HH + h) * DD;
            const float* q3 = Q + (((size_t)b * LL + p3) * HH + h) * DD;
            const float* q4 = Q + (((size_t)b * LL + p4) * HH + h) * DD;
            float c0 = 0.f, c1 = 0.f, c2 = 0.f, c3 = 0.f, c4 = 0.f;
            #pragma unroll
            for (int d4 = 0; d4 < 16; ++d4) {
                float4 kk = *(const float4*)&sK[cur][j][d4 * 4];
                int d = d4 * 4;
                c0 = fmaf(kk.x, q0[d], c0); c0 = fmaf(kk.y, q0[d+1], c0);
                c0 = fmaf(kk.z, q0[d+2], c0); c0 = fmaf(kk.w, q0[d+3], c0);
                c1 = fmaf(kk.x, q1[d], c1); c1 = fmaf(kk.y, q1[d+1], c1);
                c1 = fmaf(kk.z, q1[d+2], c1); c1 = fmaf(kk.w, q1[d+3], c1);
                c2 = fmaf(kk.x, q2[d], c2); c2 = fmaf(kk.y, q2[d+1], c2);
                c2 = fmaf(kk.z, q2[d+2], c2); c2 = fmaf(kk.w, q2[d+3], c2);
                c3 = fmaf(kk.x, q3[d], c3); c3 = fmaf(kk.y, q3[d+1], c3);
                c3 = fmaf(kk.z, q3[d+2], c3); c3 = fmaf(kk.w, q3[d+3], c3);
                c4 = fmaf(kk.x, q4[d], c4); c4 = fmaf(kk.y, q4[d+1], c4);
                c4 = fmaf(kk.z, q4[d+2], c4); c4 = fmaf(kk.w, q4[d+3], c4);
            }
            float e0 = (jg > p0) ? 0.f : __expf(c0 * 0.125f);
            float e1 = (jg > p1) ? 0.f : __expf(c1 * 0.125f);
            float e2 = (jg > p2) ? 0.f : __expf(c2 * 0.125f);
            float e3 = (jg > p3) ? 0.f : __expf(c3 * 0.125f);
            float e4 = (jg > p4) ? 0.f : __expf(c4 * 0.125f);
            sP[ub + 0][j] = e0;
            sP[ub + 1][j] = e1;
            sP[ub + 2][j] = e2;
            sP[ub + 3][j] = e3;
            sP[ub + 4][j] = e4;
            // denominator partials (wave-reduce, accumulate in registers)
            #pragma unroll
            for (int off = 1; off < 64; off <<= 1) {
                e0 += __shfl_xor(e0, off);
                e1 += __shfl_xor(e1, off);
                e2 += __shfl_xor(e2, off);
                e3 += __shfl_xor(e3, off);
                e4 += __shfl_xor(e4, off);
            }
            den[0] += e0; den[1] += e1; den[2] += e2; den[3] += e3; den[4] += e4;
        }
        __syncthreads();   // sP visible; all reads of sK[cur] done

        // ---- write staged regs to the idle buffer (overlaps with PV) ----
        if (sub + 1 < KSUB) {
            if (cur == 0) { COMMIT(1); } else { COMMIT(0); }
        }

        // ---- PV accumulate (reads sP/sV[cur] only) ----
        #pragma unroll 4
        for (int j4 = 0; j4 < KC / 4; ++j4) {
            float4 pj0 = *(const float4*)&sP[tg][j4 * 4];
            float4 pj1 = (tg < 4) ? *(const float4*)&sP[16 + tg][j4 * 4]
                                  : (float4){0,0,0,0};
            float4 va = *(const float4*)&sV[cur][j4 * 4 + 0][d4p * 4];
            float4 vb = *(const float4*)&sV[cur][j4 * 4 + 1][d4p * 4];
            float4 vc = *(const float4*)&sV[cur][j4 * 4 + 2][d4p * 4];
            float4 vd = *(const float4*)&sV[cur][j4 * 4 + 3][d4p * 4];
            a0.x = fmaf(pj0.x, va.x, fmaf(pj0.y, vb.x, fmaf(pj0.z, vc.x, fmaf(pj0.w, vd.x, a0.x))));
            a0.y = fmaf(pj0.x, va.y, fmaf(pj0.y, vb.y, fmaf(pj0.z, vc.y, fmaf(pj0.w, vd.y, a0.y))));
            a0.z = fmaf(pj0.x, va.z, fmaf(pj0.y, vb.z, fmaf(pj0.z, vc.z, fmaf(pj0.w, vd.z, a0.z))));
            a0.w = fmaf(pj0.x, va.w, fmaf(pj0.y, vb.w, fmaf(pj0.z, vc.w, fmaf(pj0.w, vd.w, a0.w))));
            a1.x = fmaf(pj1.x, va.x, fmaf(pj1.y, vb.x, fmaf(pj1.z, vc.x, fmaf(pj1.w, vd.x, a1.x))));
            a1.y = fmaf(pj1.x, va.y, fmaf(pj1.y, vb.y, fmaf(pj1.z, vc.y, fmaf(pj1.w, vd.y, a1.y))));
            a1.z = fmaf(pj1.x, va.z, fmaf(pj1.y, vb.z, fmaf(pj1.z, vc.z, fmaf(pj1.w, vd.z, a1.z))));
            a1.w = fmaf(pj1.x, va.w, fmaf(pj1.y, vb.w, fmaf(pj1.z, vc.w, fmaf(pj1.w, vd.w, a1.w))));
        }
        __syncthreads();   // PV done with sP/sV[cur]; buf^1 writes visible
    }
#undef ISSUE
#undef COMMIT

    // ---- disjoint final writes ----
    if (lane == 0) {
        int base = (bh * NCH2 + ch) * UU + ug * 20 + ub;
        Lc[base + 0] = den[0]; Lc[base + 1] = den[1]; Lc[base + 2] = den[2];
        Lc[base + 3] = den[3]; Lc[base + 4] = den[4];
    }
    {
        int u0g = ug * 20 + tg;
        size_t o0 = ((size_t)(bh * NCH2 + ch) * UU + u0g) * DD + d4p * 4;
        *(float4*)(Oc + o0) = a0;
        if (tg < 4) {
            int u1g = ug * 20 + 16 + tg;
            size_t o1 = ((size_t)(bh * NCH2 + ch) * UU + u1g) * DD + d4p * 4;
            *(float4*)(Oc + o1) = a1;
        }
    }
}

// ---------------------------------------------------------------------------
// K5: finalize — out[pos] = (sum_ch Oc) / (sum_ch Lc). After k_attn.
// Grid = 32 bh, 256 threads (wave w covers u = w*10..+9, lane = d).
// ---------------------------------------------------------------------------
__global__ void k_finalize(const float* __restrict__ Oc, const float* __restrict__ Lc,
                           const int* __restrict__ topIdx, float* __restrict__ out)
{
    int bh = blockIdx.x;
    int b  = bh / HH, h = bh % HH;
    int t  = threadIdx.x;
    int d  = t & 63, w = t >> 6;
    for (int i = 0; i < 10; ++i) {
        int u = w * 10 + i;
        int pos = topIdx[bh * UU + u];
        float num = 0.f, den = 0.f;
        #pragma unroll
        for (int c = 0; c < NCH2; ++c) {
            num += Oc[((size_t)(bh * NCH2 + c) * UU + u) * DD + d];
            den += Lc[(bh * NCH2 + c) * UU + u];
        }
        out[(((size_t)b * LL + pos) * HH + h) * DD + d] = num / den;
    }
}

// ---------------------------------------------------------------------------
extern "C" void kernel_launch(void* const* d_in, const int* in_sizes, int n_in,
                              void* d_out, int out_size, void* d_ws, size_t ws_size,
                              hipStream_t stream)
{
    const float* Q   = (const float*)d_in[0];
    const float* K   = (const float*)d_in[1];
    const float* V   = (const float*)d_in[2];
    const int*   idx = (const int*)d_in[3];
    float* out = (float*)d_out;

    // ws layout (floats) — total ~864K floats ≈ 3.45 MB (R4-proven size)
    float* M        = (float*)d_ws;                               // 65536
    int*   topIdx   = (int*)(M + (size_t)BB * HH * LL);           // 1280
    float* Oc       = (float*)(topIdx + BB * HH * UU);            // 32*8*40*64 = 655360
    float* Lc       = Oc + (size_t)BB * HH * NCH2 * UU * DD;      // 32*8*40 = 10240
    float* chunkSum = Lc + BB * HH * NCH2 * UU;                   // 131072

    k_measure_cs<<<NCSB + NMSB,        256, 0, stream>>>(Q, K, V, idx, M, chunkSum);
    k_topk_cum  <<<NTKB + NCUB,        256, 0, stream>>>(M, topIdx, V, chunkSum, out);
    k_attn      <<<BB * HH * NCH2 * UG, 256, 0, stream>>>(Q, K, V, topIdx, Oc, Lc);
    k_finalize  <<<BB * HH,            256, 0, stream>>>(Oc, Lc, topIdx, out);
}

// Round 8
// 173.871 us; speedup vs baseline: 1.2380x; 1.0795x over previous
//
#include <hip/hip_runtime.h>
#include <hip/hip_bf16.h>
#include <math.h>

// fp32 I/O confirmed. index_sample is int32.
// R9: no mega-atomic fan-in. R10: disjoint non-atomic partials (Oc/Lc).
// R11: k_attn T14 async-STAGE + LDS dbuf; k_cumsum 2-level scan.
// R12: no-op (hints ignored). R13: k_attn de-lambda WORKED; k_measure
// hints FAILED. R14: coalesced all-heads layout: shape fixed, dur same.
// R15: sched_barrier pipeline: 44.4us (best measure). R16: launch_bounds
// (256,8) spill disaster (85us); occupancy 49->75% did NOT help => not
// occupancy-limited. R17: K-tile bucketing REGRESSED (62us): 80 predicated
// branches broke load batching; no synchronized L2 window exists.
// LESSON (R12-R17, 6 attempts): ~44us is this gather structure's floor;
// the lever isn't per-wave scheduling, shape, occupancy, or ordering.
// R18: RECOVERY — revert measure role to R15 body verbatim inside the
// grid-pack (A: chunksum+measure, B: topk+cumsum). One change only; fresh
// top-5 arithmetic decides next target (topk radix vs attn ug-merge).

#define BB 4
#define LL 2048
#define HH 8
#define DD 64
#define SS 40
#define UU 40
#define CC 64
#define LC (LL/CC)    // 32 (cumsum chunking)

#define KC    64      // staged k-tile rows
#define NCH2  8       // k-chunks (256 rows each)
#define UG    2       // u-groups of 20
#define KSUB  4       // 64-row subtiles per chunk
#define KPAD  68      // K/V LDS row stride (floats)
#define PPAD  68

#define NCSB  512     // chunksum blocks in launch A (each: 4 waves x 1 chunk)
#define NMSB  (BB*LL) // measure blocks in launch A
#define NTKB  32      // topk blocks in launch B
#define NCUB  512     // cumsum blocks in launch B (each: 4 waves x 1 chunk)

// ---------------------------------------------------------------------------
// LAUNCH A: chunksum role (blocks 0..511, dispatched first, hides under
// measure) + measure role (blocks 512..8703).
// measure: block=(b,i); wave w owns samples w*10..w*10+9; 2KB sample row
// covers all 8 heads (hg=lane>>4 -> h=hg,4+hg; d4=lane&15; lane*16B).
// R15 body: depth-2 pipeline, named regs, sched_barrier(0).
// ---------------------------------------------------------------------------
__global__ void k_measure_cs(const float* __restrict__ Q, const float* __restrict__ K,
                             const float* __restrict__ V, const int* __restrict__ idx,
                             float* __restrict__ M, float* __restrict__ chunkSum)
{
    __shared__ float sMax[4][8];
    __shared__ float sSum[4][8];

    int t = threadIdx.x;

    if (blockIdx.x < NCSB) {
        // ---- chunksum role: wave handles one (bh, c) ----
        int w = t >> 6, lane = t & 63;
        int cI = blockIdx.x * 4 + w;          // 0..2047
        int bh = cI >> 6, c = cI & (CC - 1);
        int b  = bh >> 3, h = bh & 7;
        int d4 = lane & 15, rs = lane >> 4;

        float4 acc = {0,0,0,0};
        int l0 = c * LC;
        for (int l = l0 + rs; l < l0 + LC; l += 4) {
            float4 v = *(const float4*)(V + (((size_t)b * LL + l) * HH + h) * DD + d4 * 4);
            acc.x += v.x; acc.y += v.y; acc.z += v.z; acc.w += v.w;
        }
        acc.x += __shfl_xor(acc.x, 16); acc.y += __shfl_xor(acc.y, 16);
        acc.z += __shfl_xor(acc.z, 16); acc.w += __shfl_xor(acc.w, 16);
        acc.x += __shfl_xor(acc.x, 32); acc.y += __shfl_xor(acc.y, 32);
        acc.z += __shfl_xor(acc.z, 32); acc.w += __shfl_xor(acc.w, 32);
        if (lane < 16)
            *(float4*)(chunkSum + ((size_t)bh * CC + c) * DD + d4 * 4) = acc;
        return;
    }

    // ---- measure role (R15 body) ----
    int blk = blockIdx.x - NCSB;
    int b   = blk >> 11;              // / LL
    int i   = blk & (LL - 1);
    int w    = t >> 6, lane = t & 63;
    int hg   = lane >> 4;             // h group: covers h=hg and h=4+hg
    int d4   = lane & 15;             // float4 slice of d

    const int*   ip   = idx + (size_t)i * SS + w * 10;        // wave-uniform
    const float* Kb   = K + (size_t)b * (LL * HH * DD);
    const float* Qrow = Q + ((size_t)b * LL + i) * (HH * DD);

    float4 qa = *(const float4*)(Qrow + hg * DD + d4 * 4);        // h = hg
    float4 qb = *(const float4*)(Qrow + (4 + hg) * DD + d4 * 4);  // h = 4+hg

    float maxa = -INFINITY, suma = 0.f;
    float maxb = -INFINITY, sumb = 0.f;

#define DOT4(q_, k_) (fmaf((q_).w, (k_).w, fmaf((q_).z, (k_).z, \
                      fmaf((q_).y, (k_).y, (q_).x * (k_).x))))

    float4 A0, B0, A1, B1;   // current group
    float4 A2, B2, A3, B3;   // next group
    {
        int k0 = ip[0], k1 = ip[1];
        const float* r0 = Kb + (size_t)k0 * (HH * DD);
        const float* r1 = Kb + (size_t)k1 * (HH * DD);
        A0 = *(const float4*)(r0 + hg * DD + d4 * 4);
        B0 = *(const float4*)(r0 + (4 + hg) * DD + d4 * 4);
        A1 = *(const float4*)(r1 + hg * DD + d4 * 4);
        B1 = *(const float4*)(r1 + (4 + hg) * DD + d4 * 4);
    }

    #pragma unroll
    for (int g = 0; g < 5; ++g) {
        if (g < 4) {   // issue next group BEFORE computing current
            int k2 = ip[2 * g + 2], k3 = ip[2 * g + 3];
            const float* r2 = Kb + (size_t)k2 * (HH * DD);
            const float* r3 = Kb + (size_t)k3 * (HH * DD);
            A2 = *(const float4*)(r2 + hg * DD + d4 * 4);
            B2 = *(const float4*)(r2 + (4 + hg) * DD + d4 * 4);
            A3 = *(const float4*)(r3 + hg * DD + d4 * 4);
            B3 = *(const float4*)(r3 + (4 + hg) * DD + d4 * 4);
        }
        __builtin_amdgcn_sched_barrier(0);   // loads stay above

        float pa0 = DOT4(qa, A0), pb0 = DOT4(qb, B0);
        float pa1 = DOT4(qa, A1), pb1 = DOT4(qb, B1);
        #pragma unroll
        for (int off = 1; off < 16; off <<= 1) {
            pa0 += __shfl_xor(pa0, off);
            pb0 += __shfl_xor(pb0, off);
            pa1 += __shfl_xor(pa1, off);
            pb1 += __shfl_xor(pb1, off);
        }
        maxa = fmaxf(maxa, fmaxf(pa0, pa1));  suma += pa0 + pa1;
        maxb = fmaxf(maxb, fmaxf(pb0, pb1));  sumb += pb0 + pb1;

        A0 = A2; B0 = B2; A1 = A3; B1 = B3;
    }
#undef DOT4

    if (d4 == 0) {
        sMax[w][hg]     = maxa;  sSum[w][hg]     = suma;
        sMax[w][4 + hg] = maxb;  sSum[w][4 + hg] = sumb;
    }
    __syncthreads();

    if (t < 8) {
        float mx = sMax[0][t], sm = sSum[0][t];
        #pragma unroll
        for (int w2 = 1; w2 < 4; ++w2) {
            mx = fmaxf(mx, sMax[w2][t]);
            sm += sSum[w2][t];
        }
        M[((size_t)(b * HH + t)) * LL + i] = mx - sm * (1.0f / (float)LL);
    }
}

// ---------------------------------------------------------------------------
// LAUNCH B: topk role (blocks 0..31, first — blocks attn) + cumsum-scan
// role (blocks 32..543; wave handles one (bh, c); R11-proven 2-level scan).
// cumsum only needs chunkSum (launch A) => legal before attn.
// ---------------------------------------------------------------------------
__global__ void k_topk_cum(const float* __restrict__ M, int* __restrict__ topIdx,
                           const float* __restrict__ V, const float* __restrict__ chunkSum,
                           float* __restrict__ out)
{
    if (blockIdx.x < NTKB) {
        if (threadIdx.x >= 64) return;
        int lane = threadIdx.x;      // 64
        int bh   = blockIdx.x;
        const float* Mp = M + (size_t)bh * LL;

        unsigned k[32];
        #pragma unroll
        for (int r = 0; r < 32; ++r) {
            unsigned u = __float_as_uint(Mp[r * 64 + lane]);
            k[r] = (u & 0x80000000u) ? ~u : (u | 0x80000000u);  // order-preserving
        }

        unsigned T = 0u;
        for (int bit = 31; bit >= 0; --bit) {
            unsigned cand = T | (1u << bit);
            int c = 0;
            #pragma unroll
            for (int r = 0; r < 32; ++r) c += (k[r] >= cand) ? 1 : 0;
            #pragma unroll
            for (int off = 1; off < 64; off <<= 1) c += __shfl_xor(c, off);
            if (c >= UU) T = cand;
        }

        int cGT = 0, cGE = 0;
        #pragma unroll
        for (int r = 0; r < 32; ++r) {
            cGT += (k[r] > T) ? 1 : 0;
            cGE += (k[r] >= T) ? 1 : 0;
        }
        #pragma unroll
        for (int off = 1; off < 64; off <<= 1) {
            cGT += __shfl_xor(cGT, off);
            cGE += __shfl_xor(cGE, off);
        }

        int need = UU - cGT;
        int X = LL;
        if (cGE - cGT != need) {
            int lo2 = 0;
            for (int bit = 10; bit >= 0; --bit) {
                int cand = lo2 | (1 << bit);
                int c = 0;
                #pragma unroll
                for (int r = 0; r < 32; ++r)
                    c += (k[r] == T && (r * 64 + lane) < cand) ? 1 : 0;
                #pragma unroll
                for (int off = 1; off < 64; off <<= 1) c += __shfl_xor(c, off);
                if (c < need) lo2 = cand;
            }
            X = lo2 + 1;
        }

        unsigned inMask = 0u;
        int cnt = 0;
        #pragma unroll
        for (int r = 0; r < 32; ++r) {
            bool in = (k[r] > T) || (k[r] == T && (r * 64 + lane) < X);
            if (in) { inMask |= 1u << r; ++cnt; }
        }
        int pre = cnt;
        #pragma unroll
        for (int off = 1; off < 64; off <<= 1) {
            int v = __shfl_up(pre, off);
            if (lane >= off) pre += v;
        }
        int slot = pre - cnt;
        #pragma unroll
        for (int r = 0; r < 32; ++r) {
            if ((inMask >> r) & 1u) {
                topIdx[bh * UU + slot] = r * 64 + lane;
                ++slot;
            }
        }
        return;
    }

    // ---- cumsum-scan role: wave handles one (bh, c) ----
    int t    = threadIdx.x;
    int w    = t >> 6, lane = t & 63;
    int cI   = (blockIdx.x - NTKB) * 4 + w;   // 0..2047
    int c    = cI & (CC - 1);
    int bh   = cI >> 6;
    int b    = bh >> 3, h = bh & 7;
    int d4   = lane & 15, s = lane >> 4;      // s: subsegment 0..3 (8 rows each)

    const float4* CS4 = (const float4*)chunkSum;
    float4 off = {0,0,0,0};
    for (int c2 = s; c2 < c; c2 += 4) {
        float4 x = CS4[((size_t)bh * CC + c2) * 16 + d4];
        off.x += x.x; off.y += x.y; off.z += x.z; off.w += x.w;
    }
    off.x += __shfl_xor(off.x, 16); off.y += __shfl_xor(off.y, 16);
    off.z += __shfl_xor(off.z, 16); off.w += __shfl_xor(off.w, 16);
    off.x += __shfl_xor(off.x, 32); off.y += __shfl_xor(off.y, 32);
    off.z += __shfl_xor(off.z, 32); off.w += __shfl_xor(off.w, 32);

    int l0 = c * LC + s * 8;
    size_t base = (((size_t)b * LL + l0) * HH + h) * DD + d4 * 4;
    const size_t stride = (size_t)HH * DD;

    float4 v[8];
    #pragma unroll
    for (int r = 0; r < 8; ++r)
        v[r] = *(const float4*)(V + base + (size_t)r * stride);
    #pragma unroll
    for (int r = 1; r < 8; ++r) {
        v[r].x += v[r-1].x; v[r].y += v[r-1].y;
        v[r].z += v[r-1].z; v[r].w += v[r-1].w;
    }

    float4 inc = v[7];
    float4 p1;
    p1.x = __shfl_up(inc.x, 16); p1.y = __shfl_up(inc.y, 16);
    p1.z = __shfl_up(inc.z, 16); p1.w = __shfl_up(inc.w, 16);
    if (s >= 1) { inc.x += p1.x; inc.y += p1.y; inc.z += p1.z; inc.w += p1.w; }
    float4 p2;
    p2.x = __shfl_up(inc.x, 32); p2.y = __shfl_up(inc.y, 32);
    p2.z = __shfl_up(inc.z, 32); p2.w = __shfl_up(inc.w, 32);
    if (s >= 2) { inc.x += p2.x; inc.y += p2.y; inc.z += p2.z; inc.w += p2.w; }

    float4 add;
    add.x = off.x + inc.x - v[7].x;
    add.y = off.y + inc.y - v[7].y;
    add.z = off.z + inc.z - v[7].z;
    add.w = off.w + inc.w - v[7].w;

    #pragma unroll
    for (int r = 0; r < 8; ++r) {
        float4 o;
        o.x = v[r].x + add.x; o.y = v[r].y + add.y;
        o.z = v[r].z + add.z; o.w = v[r].w + add.w;
        *(float4*)(out + base + (size_t)r * stride) = o;
    }
}

// ---------------------------------------------------------------------------
// K3: attention partials, shift-free softmax, NON-ATOMIC disjoint writes.
// Grid = bh(32) x ch(8) x ug(2) = 512 blocks, 256 threads, 2/CU resident.
// Double-buffered LDS + async-STAGE split (T14). Staging in 8 NAMED float4
// registers (macros, no lambdas/arrays) — R13-proven (killed 64MB scratch).
// ---------------------------------------------------------------------------
__launch_bounds__(256, 2)
__global__ void k_attn(const float* __restrict__ Q, const float* __restrict__ K,
                       const float* __restrict__ V, const int* __restrict__ topIdx,
                       float* __restrict__ Oc, float* __restrict__ Lc)
{
    __shared__ float sK[2][KC][KPAD];
    __shared__ float sV[2][KC][KPAD];
    __shared__ float sP[20][PPAD];
    __shared__ int   sPos[UU];

    int t   = threadIdx.x;
    int bid = blockIdx.x;
    int bh  = bid / (NCH2 * UG);
    int rem = bid % (NCH2 * UG);
    int ch  = rem / UG, ug = rem % UG;
    int b   = bh / HH, h = bh % HH;

    if (t < UU) sPos[t] = topIdx[bh * UU + t];

    int j  = t & 63;                 // QK lane -> k-row within subtile
    int w  = t >> 6, lane = t & 63;  // wave mapping
    int ub = __builtin_amdgcn_readfirstlane(w) * 5;   // local u base (0,5,10,15)

    // PV accumulators: thread = (d4p = t&15, tg = t>>4); local u = tg, 16+tg
    int d4p = t & 15, tg = t >> 4;
    float4 a0 = {0,0,0,0}, a1 = {0,0,0,0};
    float den[5] = {0.f, 0.f, 0.f, 0.f, 0.f};

    const float* Kh = K + ((size_t)b * LL * HH + h) * DD;
    const float* Vh = V + ((size_t)b * LL * HH + h) * DD;

    // staged tile in 8 NAMED float4 regs; thread covers rows it*16+tg, slice d4p
    float4 pk0, pk1, pk2, pk3, pv0, pv1, pv2, pv3;

#define ISSUE(k0_) { \
    size_t g0 = (size_t)((k0_) +  0 + tg) * (HH * DD) + d4p * 4; \
    size_t g1 = (size_t)((k0_) + 16 + tg) * (HH * DD) + d4p * 4; \
    size_t g2 = (size_t)((k0_) + 32 + tg) * (HH * DD) + d4p * 4; \
    size_t g3 = (size_t)((k0_) + 48 + tg) * (HH * DD) + d4p * 4; \
    pk0 = *(const float4*)(Kh + g0); pv0 = *(const float4*)(Vh + g0); \
    pk1 = *(const float4*)(Kh + g1); pv1 = *(const float4*)(Vh + g1); \
    pk2 = *(const float4*)(Kh + g2); pv2 = *(const float4*)(Vh + g2); \
    pk3 = *(const float4*)(Kh + g3); pv3 = *(const float4*)(Vh + g3); \
}
#define COMMIT(buf_) { \
    *(float4*)&sK[buf_][ 0 + tg][d4p * 4] = pk0; *(float4*)&sV[buf_][ 0 + tg][d4p * 4] = pv0; \
    *(float4*)&sK[buf_][16 + tg][d4p * 4] = pk1; *(float4*)&sV[buf_][16 + tg][d4p * 4] = pv1; \
    *(float4*)&sK[buf_][32 + tg][d4p * 4] = pk2; *(float4*)&sV[buf_][32 + tg][d4p * 4] = pv2; \
    *(float4*)&sK[buf_][48 + tg][d4p * 4] = pk3; *(float4*)&sV[buf_][48 + tg][d4p * 4] = pv3; \
}

    int k0base = ch * KSUB * KC;
    ISSUE(k0base);
    COMMIT(0);
    __syncthreads();   // buf0 + sPos ready

    #pragma unroll
    for (int sub = 0; sub < KSUB; ++sub) {
        int cur = sub & 1;
        int k0  = k0base + sub * KC;

        if (sub + 1 < KSUB) ISSUE(k0 + KC);   // async: in flight across QK

        // ---- QK: lane owns k-row j; Q rows via scalar (wave-uniform) loads ----
        int jg = k0 + j;
        {
            int p0 = __builtin_amdgcn_readfirstlane(sPos[ug * 20 + ub + 0]);
            int p1 = __builtin_amdgcn_readfirstlane(sPos[ug * 20 + ub + 1]);
            int p2 = __builtin_amdgcn_readfirstlane(sPos[ug * 20 + ub + 2]);
            int p3 = __builtin_amdgcn_readfirstlane(sPos[ug * 20 + ub + 3]);
            int p4 = __builtin_amdgcn_readfirstlane(sPos[ug * 20 + ub + 4]);
            const float* q0 = Q + (((size_t)b * LL + p0) * HH + h) * DD;
            const float* q1 = Q + (((size_t)b * LL + p1) * HH + h) * DD;
            const float* q2 = Q + (((size_t)b * LL + p2) * HH + h) * DD;
            const float* q3 = Q + (((size_t)b * LL + p3) * HH + h) * DD;
            const float* q4 = Q + (((size_t)b * LL + p4) * HH + h) * DD;
            float c0 = 0.f, c1 = 0.f, c2 = 0.f, c3 = 0.f, c4 = 0.f;
            #pragma unroll
            for (int d4 = 0; d4 < 16; ++d4) {
                float4 kk = *(const float4*)&sK[cur][j][d4 * 4];
                int d = d4 * 4;
                c0 = fmaf(kk.x, q0[d], c0); c0 = fmaf(kk.y, q0[d+1], c0);
                c0 = fmaf(kk.z, q0[d+2], c0); c0 = fmaf(kk.w, q0[d+3], c0);
                c1 = fmaf(kk.x, q1[d], c1); c1 = fmaf(kk.y, q1[d+1], c1);
                c1 = fmaf(kk.z, q1[d+2], c1); c1 = fmaf(kk.w, q1[d+3], c1);
                c2 = fmaf(kk.x, q2[d], c2); c2 = fmaf(kk.y, q2[d+1], c2);
                c2 = fmaf(kk.z, q2[d+2], c2); c2 = fmaf(kk.w, q2[d+3], c2);
                c3 = fmaf(kk.x, q3[d], c3); c3 = fmaf(kk.y, q3[d+1], c3);
                c3 = fmaf(kk.z, q3[d+2], c3); c3 = fmaf(kk.w, q3[d+3], c3);
                c4 = fmaf(kk.x, q4[d], c4); c4 = fmaf(kk.y, q4[d+1], c4);
                c4 = fmaf(kk.z, q4[d+2], c4); c4 = fmaf(kk.w, q4[d+3], c4);
            }
            float e0 = (jg > p0) ? 0.f : __expf(c0 * 0.125f);
            float e1 = (jg > p1) ? 0.f : __expf(c1 * 0.125f);
            float e2 = (jg > p2) ? 0.f : __expf(c2 * 0.125f);
            float e3 = (jg > p3) ? 0.f : __expf(c3 * 0.125f);
            float e4 = (jg > p4) ? 0.f : __expf(c4 * 0.125f);
            sP[ub + 0][j] = e0;
            sP[ub + 1][j] = e1;
            sP[ub + 2][j] = e2;
            sP[ub + 3][j] = e3;
            sP[ub + 4][j] = e4;
            // denominator partials (wave-reduce, accumulate in registers)
            #pragma unroll
            for (int off = 1; off < 64; off <<= 1) {
                e0 += __shfl_xor(e0, off);
                e1 += __shfl_xor(e1, off);
                e2 += __shfl_xor(e2, off);
                e3 += __shfl_xor(e3, off);
                e4 += __shfl_xor(e4, off);
            }
            den[0] += e0; den[1] += e1; den[2] += e2; den[3] += e3; den[4] += e4;
        }
        __syncthreads();   // sP visible; all reads of sK[cur] done

        // ---- write staged regs to the idle buffer (overlaps with PV) ----
        if (sub + 1 < KSUB) {
            if (cur == 0) { COMMIT(1); } else { COMMIT(0); }
        }

        // ---- PV accumulate (reads sP/sV[cur] only) ----
        #pragma unroll 4
        for (int j4 = 0; j4 < KC / 4; ++j4) {
            float4 pj0 = *(const float4*)&sP[tg][j4 * 4];
            float4 pj1 = (tg < 4) ? *(const float4*)&sP[16 + tg][j4 * 4]
                                  : (float4){0,0,0,0};
            float4 va = *(const float4*)&sV[cur][j4 * 4 + 0][d4p * 4];
            float4 vb = *(const float4*)&sV[cur][j4 * 4 + 1][d4p * 4];
            float4 vc = *(const float4*)&sV[cur][j4 * 4 + 2][d4p * 4];
            float4 vd = *(const float4*)&sV[cur][j4 * 4 + 3][d4p * 4];
            a0.x = fmaf(pj0.x, va.x, fmaf(pj0.y, vb.x, fmaf(pj0.z, vc.x, fmaf(pj0.w, vd.x, a0.x))));
            a0.y = fmaf(pj0.x, va.y, fmaf(pj0.y, vb.y, fmaf(pj0.z, vc.y, fmaf(pj0.w, vd.y, a0.y))));
            a0.z = fmaf(pj0.x, va.z, fmaf(pj0.y, vb.z, fmaf(pj0.z, vc.z, fmaf(pj0.w, vd.z, a0.z))));
            a0.w = fmaf(pj0.x, va.w, fmaf(pj0.y, vb.w, fmaf(pj0.z, vc.w, fmaf(pj0.w, vd.w, a0.w))));
            a1.x = fmaf(pj1.x, va.x, fmaf(pj1.y, vb.x, fmaf(pj1.z, vc.x, fmaf(pj1.w, vd.x, a1.x))));
            a1.y = fmaf(pj1.x, va.y, fmaf(pj1.y, vb.y, fmaf(pj1.z, vc.y, fmaf(pj1.w, vd.y, a1.y))));
            a1.z = fmaf(pj1.x, va.z, fmaf(pj1.y, vb.z, fmaf(pj1.z, vc.z, fmaf(pj1.w, vd.z, a1.z))));
            a1.w = fmaf(pj1.x, va.w, fmaf(pj1.y, vb.w, fmaf(pj1.z, vc.w, fmaf(pj1.w, vd.w, a1.w))));
        }
        __syncthreads();   // PV done with sP/sV[cur]; buf^1 writes visible
    }
#undef ISSUE
#undef COMMIT

    // ---- disjoint final writes ----
    if (lane == 0) {
        int base = (bh * NCH2 + ch) * UU + ug * 20 + ub;
        Lc[base + 0] = den[0]; Lc[base + 1] = den[1]; Lc[base + 2] = den[2];
        Lc[base + 3] = den[3]; Lc[base + 4] = den[4];
    }
    {
        int u0g = ug * 20 + tg;
        size_t o0 = ((size_t)(bh * NCH2 + ch) * UU + u0g) * DD + d4p * 4;
        *(float4*)(Oc + o0) = a0;
        if (tg < 4) {
            int u1g = ug * 20 + 16 + tg;
            size_t o1 = ((size_t)(bh * NCH2 + ch) * UU + u1g) * DD + d4p * 4;
            *(float4*)(Oc + o1) = a1;
        }
    }
}

// ---------------------------------------------------------------------------
// K5: finalize — out[pos] = (sum_ch Oc) / (sum_ch Lc). After k_attn.
// Grid = 32 bh, 256 threads (wave w covers u = w*10..+9, lane = d).
// ---------------------------------------------------------------------------
__global__ void k_finalize(const float* __restrict__ Oc, const float* __restrict__ Lc,
                           const int* __restrict__ topIdx, float* __restrict__ out)
{
    int bh = blockIdx.x;
    int b  = bh / HH, h = bh % HH;
    int t  = threadIdx.x;
    int d  = t & 63, w = t >> 6;
    for (int i = 0; i < 10; ++i) {
        int u = w * 10 + i;
        int pos = topIdx[bh * UU + u];
        float num = 0.f, den = 0.f;
        #pragma unroll
        for (int c = 0; c < NCH2; ++c) {
            num += Oc[((size_t)(bh * NCH2 + c) * UU + u) * DD + d];
            den += Lc[(bh * NCH2 + c) * UU + u];
        }
        out[(((size_t)b * LL + pos) * HH + h) * DD + d] = num / den;
    }
}

// ---------------------------------------------------------------------------
extern "C" void kernel_launch(void* const* d_in, const int* in_sizes, int n_in,
                              void* d_out, int out_size, void* d_ws, size_t ws_size,
                              hipStream_t stream)
{
    const float* Q   = (const float*)d_in[0];
    const float* K   = (const float*)d_in[1];
    const float* V   = (const float*)d_in[2];
    const int*   idx = (const int*)d_in[3];
    float* out = (float*)d_out;

    // ws layout (floats) — total ~864K floats ≈ 3.45 MB (R4-proven size)
    float* M        = (float*)d_ws;                               // 65536
    int*   topIdx   = (int*)(M + (size_t)BB * HH * LL);           // 1280
    float* Oc       = (float*)(topIdx + BB * HH * UU);            // 32*8*40*64 = 655360
    float* Lc       = Oc + (size_t)BB * HH * NCH2 * UU * DD;      // 32*8*40 = 10240
    float* chunkSum = Lc + BB * HH * NCH2 * UU;                   // 131072

    k_measure_cs<<<NCSB + NMSB,        256, 0, stream>>>(Q, K, V, idx, M, chunkSum);
    k_topk_cum  <<<NTKB + NCUB,        256, 0, stream>>>(M, topIdx, V, chunkSum, out);
    k_attn      <<<BB * HH * NCH2 * UG, 256, 0, stream>>>(Q, K, V, topIdx, Oc, Lc);
    k_finalize  <<<BB * HH,            256, 0, stream>>>(Oc, Lc, topIdx, out);
}